// Round 6
// baseline (356.904 us; speedup 1.0000x reference)
//
#include <hip/hip_runtime.h>
#include <hip/hip_bf16.h>
#include <stdint.h>

typedef unsigned short u16;
typedef unsigned int u32;
typedef __attribute__((ext_vector_type(8))) short bf16x8;
typedef __attribute__((ext_vector_type(4))) float f32x4;

typedef __attribute__((address_space(3))) void lds_void;
typedef const __attribute__((address_space(1))) void gbl_void;

#define SIDE 4194304u   // 4M elems = one side's [B,H,2048,64] / [4096,1024]
#define BHSTR 131072u   // 2048*64 per (b,h)
#define QK_SCALE 0.18033688011112042f  // 0.125 * log2(e): folded so exp(x/8)=2^(x')

static __device__ __forceinline__ u16 f2bf(float f) {
  union { __hip_bfloat16 b; u16 u; } cv;
  cv.b = __float2bfloat16(f);
  return cv.u;
}
static __device__ __forceinline__ float bf2f(u16 u) {
  union { __hip_bfloat16 b; u16 u; } cv;
  cv.u = u;
  return __bfloat162float(cv.b);
}
static __device__ __forceinline__ u32 pk2bf(float x, float y) {
  float2 f = {x, y};
  union { __hip_bfloat162 b; u32 u; } cv;
  cv.b = __float22bfloat162_rn(f);
  return cv.u;
}

// ---------------- fused prep: input cvt + bias cvt + weight transpose -----
// blocks [0,4096): a,b fp32->bf16 ; [4096,4120): biases ; [4120,5656): weights
__global__ __launch_bounds__(256) void k_prep(
    const float* __restrict__ a, const float* __restrict__ b, u16* __restrict__ ab,
    const float* w0, const float* w1, const float* w2, const float* w3,
    const float* w4, const float* w5, u16* __restrict__ wt,
    const float* b0, const float* b1, const float* b2, const float* b3,
    const float* b4, const float* b5, u16* __restrict__ bias) {
  __shared__ u16 tile[64][72];
  int bid = blockIdx.x;
  int tid = threadIdx.x;
  if (bid < 4096) {
    int z = bid >> 11;
    const float* src = z ? b : a;
    size_t i = ((size_t)(bid & 2047) * 256 + tid) * 8;
    float4 x0 = *(const float4*)(src + i);
    float4 x1 = *(const float4*)(src + i + 4);
    uint4 o = {pk2bf(x0.x, x0.y), pk2bf(x0.z, x0.w),
               pk2bf(x1.x, x1.y), pk2bf(x1.z, x1.w)};
    *(uint4*)(ab + (size_t)z * SIDE + i) = o;
    return;
  }
  if (bid < 4120) {
    const float* srcs[6] = {b0, b1, b2, b3, b4, b5};
    int t = bid - 4096;
    int z = t >> 2;
    int i = (t & 3) * 256 + tid;
    float sc = (z == 0) ? QK_SCALE : 1.0f;
    bias[z * 1024 + i] = f2bf(srcs[z][i] * sc);
    return;
  }
  {
    const float* srcs[6] = {w0, w1, w2, w3, w4, w5};
    int t = bid - 4120;
    int z = t >> 8;
    int bx = t & 15, by = (t >> 4) & 15;
    float sc = (z == 0) ? QK_SCALE : 1.0f;
    const float* src = srcs[z] + (size_t)(by * 64) * 1024 + bx * 64;
    int row = tid >> 2, c4 = tid & 3;
#pragma unroll
    for (int p = 0; p < 2; ++p) {
      int col = c4 * 8 + p * 32;
      const float* sf = src + (size_t)row * 1024 + col;
      float4 x0 = *(const float4*)sf;
      float4 x1 = *(const float4*)(sf + 4);
      uint4 o = {pk2bf(x0.x * sc, x0.y * sc), pk2bf(x0.z * sc, x0.w * sc),
                 pk2bf(x1.x * sc, x1.y * sc), pk2bf(x1.z * sc, x1.w * sc)};
      *(uint4*)(&tile[row][col]) = o;
    }
    __syncthreads();
    u16* dst = wt + (size_t)z * 1048576u + (size_t)(bx * 64) * 1024 + by * 64;
#pragma unroll
    for (int p = 0; p < 2; ++p) {
      int col = c4 * 8 + p * 32;
      u16 tmp[8];
#pragma unroll
      for (int i = 0; i < 8; ++i) tmp[i] = tile[col + i][row];
      *(uint4*)(dst + (size_t)row * 1024 + col) = *(uint4*)tmp;
    }
  }
}

// ---------------- QKV projection: [4096,1024]bf16 @ WtAB[2048,1024]^T -----
__global__ __launch_bounds__(256) void k_gemm_qkv(
    const u16* __restrict__ Aall, const u16* __restrict__ WtA,
    const u16* __restrict__ WtB, const u16* __restrict__ bias,
    u16* __restrict__ qkbuf, u16* __restrict__ vbuf) {
  __shared__ u16 Sh[8192];
  u16* As = Sh;
  u16* Bs = Sh + 4096;
  int tid = threadIdx.x;
  int wave = tid >> 6, lane = tid & 63;
  int quad = lane >> 4, lrow = lane & 15;
  int wr = wave >> 1, wc = wave & 1;
  int z = blockIdx.z;
  int m0 = blockIdx.y * 128, n0 = blockIdx.x * 128;
  const u16* A = Aall + (size_t)z * SIDE;
  const u16* Wt = z ? WtB : WtA;
  const u16* bi = bias + (size_t)z * 2048;

  f32x4 acc[4][4] = {};
  int srow = 32 * wave + (lane >> 2);
  int scol = (lane & 3) * 8;
  const u16* gA = A + (size_t)(m0 + srow) * 1024 + scol;
  const u16* gB = Wt + (size_t)(n0 + srow) * 1024 + scol;
  u16* lA = &As[(32 * wave) * 32];
  u16* lB = &Bs[(32 * wave) * 32];

  for (int k0 = 0; k0 < 1024; k0 += 32) {
    __syncthreads();
#pragma unroll
    for (int j = 0; j < 2; ++j) {
      __builtin_amdgcn_global_load_lds((gbl_void*)(gA + (size_t)(16 * j) * 1024 + k0),
                                       (lds_void*)(lA + 16 * j * 32), 16, 0, 0);
      __builtin_amdgcn_global_load_lds((gbl_void*)(gB + (size_t)(16 * j) * 1024 + k0),
                                       (lds_void*)(lB + 16 * j * 32), 16, 0, 0);
    }
    __syncthreads();
    bf16x8 af[4], bfr[4];
#pragma unroll
    for (int i = 0; i < 4; ++i)
      af[i] = *(const bf16x8*)&As[(64 * wr + 16 * i + lrow) * 32 + 8 * quad];
#pragma unroll
    for (int j = 0; j < 4; ++j)
      bfr[j] = *(const bf16x8*)&Bs[(64 * wc + 16 * j + lrow) * 32 + 8 * quad];
#pragma unroll
    for (int i = 0; i < 4; ++i)
#pragma unroll
      for (int j = 0; j < 4; ++j)
        acc[i][j] = __builtin_amdgcn_mfma_f32_16x16x32_bf16(af[i], bfr[j], acc[i][j], 0, 0, 0);
  }

  float bv[4];
#pragma unroll
  for (int j = 0; j < 4; ++j) bv[j] = bf2f(bi[n0 + 64 * wc + 16 * j + lrow]);

  int x = blockIdx.x;
  bool isv = (x >= 8);
  int h = (isv ? 2 * (x - 8) : 2 * x) + wc;
  u16* dst = (isv ? vbuf : qkbuf) + (size_t)z * SIDE;
  u16* lw = Sh + wave * 1216;  // 16 rows * stride 76 per wave

  __syncthreads();
#pragma unroll
  for (int i = 0; i < 4; ++i) {
#pragma unroll
    for (int j = 0; j < 4; ++j)
#pragma unroll
      for (int r = 0; r < 4; ++r)
        lw[(4 * quad + r) * 76 + 16 * j + lrow] = f2bf(acc[i][j][r] + bv[j]);
    asm volatile("s_waitcnt lgkmcnt(0)" ::: "memory");
    int row = lane >> 2, cg = (lane & 3) * 16;
    int rg = m0 + 64 * wr + 16 * i + row;
    int bb = rg >> 11, rl = rg & 2047;
    u16* dr = dst + (size_t)(bb * 16 + h) * BHSTR + (size_t)rl * 64 + cg;
    uint2 w0 = *(const uint2*)&lw[row * 76 + cg];
    uint2 w1 = *(const uint2*)&lw[row * 76 + cg + 4];
    uint2 w2 = *(const uint2*)&lw[row * 76 + cg + 8];
    uint2 w3 = *(const uint2*)&lw[row * 76 + cg + 12];
    uint4 o0 = {w0.x, w0.y, w1.x, w1.y};
    uint4 o1 = {w2.x, w2.y, w3.x, w3.y};
    *(uint4*)dr = o0;
    *(uint4*)(dr + 8) = o1;
    asm volatile("s_waitcnt lgkmcnt(0)" ::: "memory");
  }
}

// ---------------- V transpose per head: [sbh][2048][64] -> [sbh][64][2048] --
__global__ __launch_bounds__(256) void k_transpose_v(const u16* __restrict__ v,
                                                     u16* __restrict__ vt) {
  __shared__ u16 tile[64][72];
  int sbh = blockIdx.y;
  int n0 = blockIdx.x * 64;
  const u16* src = v + (size_t)sbh * BHSTR + (size_t)n0 * 64;
  u16* dst = vt + (size_t)sbh * BHSTR + n0;
  int t = threadIdx.x;
  int row = t >> 2, c4 = t & 3;
#pragma unroll
  for (int p = 0; p < 2; ++p) {
    int col = c4 * 8 + p * 32;
    uint4 q = *(const uint4*)(src + (size_t)row * 64 + col);
    *(uint4*)(&tile[row][col]) = q;
  }
  __syncthreads();
#pragma unroll
  for (int p = 0; p < 2; ++p) {
    int col = c4 * 8 + p * 32;
    u16 tmp[8];
#pragma unroll
    for (int i = 0; i < 8; ++i) tmp[i] = tile[col + i][row];
    *(uint4*)(dst + (size_t)row * 2048 + col) = *(uint4*)tmp;
  }
}

// ---------------- fused dual-softmax attention, both sides ----------------
// z=0: Q=aq,K=bq,V=bv -> a_ctx ; z=1: Q=bq,K=aq,V=av -> b_ctx
// Q A-frags direct from global; K/V double-buffered DMA; P via 8KB LDS in
// two 32-s halves with xor-slot swizzle (4-pass minimum, conflict-free).
// LDS = 16+16+8 = 40KB exactly -> 4 blocks/CU, grid 1024 = full residency.
__global__ __launch_bounds__(256) void k_attn(
    const u16* __restrict__ qk, const u16* __restrict__ vt,
    u16* __restrict__ ctx) {
  __shared__ u16 Ks[2 * 4096];
  __shared__ u16 Vs[2 * 4096];
  __shared__ u16 Ps[128 * 32];
  int tid = threadIdx.x;
  int wave = tid >> 6, lane = tid & 63;
  int quad = lane >> 4, lrow = lane & 15;
  int z = blockIdx.z, bh = blockIdx.x;  // x=bh: l-tiles of one (z,bh) share an XCD
  int l0 = blockIdx.y * 128;
  const u16* Qb = qk + (size_t)z * SIDE + (size_t)bh * BHSTR + (size_t)l0 * 64;
  const u16* Kb = qk + (size_t)(1 - z) * SIDE + (size_t)bh * BHSTR;
  const u16* Vtb = vt + (size_t)(1 - z) * SIDE + (size_t)bh * BHSTR;

  // Q A-fragments straight from global: contiguous aligned 16B per lane
  bf16x8 qf[2][2];
#pragma unroll
  for (int rt = 0; rt < 2; ++rt)
#pragma unroll
    for (int d = 0; d < 2; ++d)
      qf[rt][d] = *(const bf16x8*)(Qb + (size_t)(32 * wave + 16 * rt + lrow) * 64 +
                                   32 * d + 8 * quad);

  // stage K/V round 0 into buffer 0 (granule-swizzled)
#pragma unroll
  for (int p = 0; p < 2; ++p) {
    int G0 = p * 256 + wave * 64;
    int G = G0 + lane;
    int row = G >> 3, c = G & 7;
    int sw = (c ^ (row & 7)) * 8;
    __builtin_amdgcn_global_load_lds((gbl_void*)(Kb + (size_t)row * 64 + sw),
                                     (lds_void*)(Ks + G0 * 8), 16, 0, 0);
    __builtin_amdgcn_global_load_lds((gbl_void*)(Vtb + (size_t)row * 2048 + sw),
                                     (lds_void*)(Vs + G0 * 8), 16, 0, 0);
  }

  f32x4 cacc[2][4] = {};
  float rsum[2] = {0.f, 0.f};
  int key = (lrow >> 1) & 7;  // Ps slot xor key

  for (int it = 0; it < 32; ++it) {
    __syncthreads();  // drains in-flight DMA (issued a full round ago)
    int prty = it & 1;
    if (it + 1 < 32) {  // prefetch next round into other buffer
      int s1 = (it + 1) << 6;
      int nb = (1 - prty) * 4096;
#pragma unroll
      for (int p = 0; p < 2; ++p) {
        int G0 = p * 256 + wave * 64;
        int G = G0 + lane;
        int row = G >> 3, c = G & 7;
        int sw = (c ^ (row & 7)) * 8;
        __builtin_amdgcn_global_load_lds((gbl_void*)(Kb + (size_t)(s1 + row) * 64 + sw),
                                         (lds_void*)(Ks + nb + G0 * 8), 16, 0, 0);
        __builtin_amdgcn_global_load_lds((gbl_void*)(Vtb + (size_t)row * 2048 + s1 + sw),
                                         (lds_void*)(Vs + nb + G0 * 8), 16, 0, 0);
      }
    }
    const u16* KsC = Ks + prty * 4096;
    const u16* VsC = Vs + prty * 4096;
#pragma unroll
    for (int h = 0; h < 2; ++h) {
      // S^T = K·Q^T for this 32-s half; exp2 (scale folded); packed b64 -> Ps
#pragma unroll
      for (int jj = 0; jj < 2; ++jj) {
        int j = 2 * h + jj;
        int kr = 16 * j + lrow;
        bf16x8 kf0 = *(const bf16x8*)&KsC[(kr * 8 + (quad ^ (kr & 7))) * 8];
        bf16x8 kf1 = *(const bf16x8*)&KsC[(kr * 8 + ((quad + 4) ^ (kr & 7))) * 8];
#pragma unroll
        for (int rt = 0; rt < 2; ++rt) {
          f32x4 s = {};
          s = __builtin_amdgcn_mfma_f32_16x16x32_bf16(kf0, qf[rt][0], s, 0, 0, 0);
          s = __builtin_amdgcn_mfma_f32_16x16x32_bf16(kf1, qf[rt][1], s, 0, 0, 0);
          float e0 = __builtin_exp2f(s[0]);
          float e1 = __builtin_exp2f(s[1]);
          float e2 = __builtin_exp2f(s[2]);
          float e3 = __builtin_exp2f(s[3]);
          rsum[rt] += (e0 + e1) + (e2 + e3);
          uint2 pk = {pk2bf(e0, e1), pk2bf(e2, e3)};
          int slot = (4 * jj + quad) ^ key;
          *(uint2*)&Ps[(32 * wave + 16 * rt + lrow) * 32 + slot * 4] = pk;
        }
      }
      asm volatile("s_waitcnt lgkmcnt(0)" ::: "memory");  // wave-private round-trip
      bf16x8 pf[2];
#pragma unroll
      for (int rt = 0; rt < 2; ++rt) {
        const u16* pr = &Ps[(32 * wave + 16 * rt + lrow) * 32];
        uint2 lo = *(const uint2*)&pr[((2 * quad) ^ key) * 4];
        uint2 hi = *(const uint2*)&pr[((2 * quad + 1) ^ key) * 4];
        union { uint4 u; bf16x8 v; } cv;
        cv.u = (uint4){lo.x, lo.y, hi.x, hi.y};
        pf[rt] = cv.v;
      }
      // P @ V for this half (K=32)
#pragma unroll
      for (int j2 = 0; j2 < 4; ++j2) {
        int vr = 16 * j2 + lrow;
        bf16x8 vfh = *(const bf16x8*)&VsC[(vr * 8 + ((4 * h + quad) ^ (vr & 7))) * 8];
#pragma unroll
        for (int rt = 0; rt < 2; ++rt)
          cacc[rt][j2] = __builtin_amdgcn_mfma_f32_16x16x32_bf16(pf[rt], vfh, cacc[rt][j2], 0, 0, 0);
      }
    }
  }

  float rinv[2][4];
#pragma unroll
  for (int rt = 0; rt < 2; ++rt) {
    float v = rsum[rt];
    v += __shfl_xor(v, 16);
    v += __shfl_xor(v, 32);
    float rv = 1.0f / v;
#pragma unroll
    for (int r = 0; r < 4; ++r)
      rinv[rt][r] = __shfl(rv, 20 * quad + r);  // lane holding total for l_local=4q+r
  }

  int bb = bh >> 4, hh = bh & 15;
  u16* Ob = ctx + (size_t)z * SIDE + (size_t)(bb * 2048 + l0) * 1024 + hh * 64;
#pragma unroll
  for (int rt = 0; rt < 2; ++rt)
#pragma unroll
    for (int r = 0; r < 4; ++r) {
      int l = 32 * wave + 16 * rt + 4 * quad + r;
#pragma unroll
      for (int j = 0; j < 4; ++j)
        Ob[(size_t)l * 1024 + 16 * j + lrow] = f2bf(cacc[rt][j][r] * rinv[rt][r]);
    }
}

// ---------------- O projection: ctx[4096,1024]bf16 @ WtO^T + bias -> fp32 --
__global__ __launch_bounds__(256) void k_gemm_o(
    const u16* __restrict__ ctx, const u16* __restrict__ WtO,
    const u16* __restrict__ bias, float* __restrict__ out) {
  __shared__ u16 As[128 * 32];
  __shared__ u16 Bs[128 * 32];
  int tid = threadIdx.x;
  int wave = tid >> 6, lane = tid & 63;
  int quad = lane >> 4, lrow = lane & 15;
  int wr = wave >> 1, wc = wave & 1;
  int z = blockIdx.z;
  int m0 = blockIdx.y * 128, n0 = blockIdx.x * 128;
  const u16* A = ctx + (size_t)z * SIDE;
  const u16* Wt = WtO + (size_t)z * 1048576;
  const u16* bi = bias + (size_t)z * 1024;
  float* C = out + (size_t)z * SIDE;

  f32x4 acc[4][4] = {};
  int srow = 32 * wave + (lane >> 2);
  int scol = (lane & 3) * 8;
  const u16* gA = A + (size_t)(m0 + srow) * 1024 + scol;
  const u16* gB = Wt + (size_t)(n0 + srow) * 1024 + scol;
  u16* lA = &As[(32 * wave) * 32];
  u16* lB = &Bs[(32 * wave) * 32];

  for (int k0 = 0; k0 < 1024; k0 += 32) {
    __syncthreads();
#pragma unroll
    for (int j = 0; j < 2; ++j) {
      __builtin_amdgcn_global_load_lds((gbl_void*)(gA + (size_t)(16 * j) * 1024 + k0),
                                       (lds_void*)(lA + 16 * j * 32), 16, 0, 0);
      __builtin_amdgcn_global_load_lds((gbl_void*)(gB + (size_t)(16 * j) * 1024 + k0),
                                       (lds_void*)(lB + 16 * j * 32), 16, 0, 0);
    }
    __syncthreads();
    bf16x8 af[4], bfr[4];
#pragma unroll
    for (int i = 0; i < 4; ++i)
      af[i] = *(const bf16x8*)&As[(64 * wr + 16 * i + lrow) * 32 + 8 * quad];
#pragma unroll
    for (int j = 0; j < 4; ++j)
      bfr[j] = *(const bf16x8*)&Bs[(64 * wc + 16 * j + lrow) * 32 + 8 * quad];
#pragma unroll
    for (int i = 0; i < 4; ++i)
#pragma unroll
      for (int j = 0; j < 4; ++j)
        acc[i][j] = __builtin_amdgcn_mfma_f32_16x16x32_bf16(af[i], bfr[j], acc[i][j], 0, 0, 0);
  }

  float bv[4];
#pragma unroll
  for (int j = 0; j < 4; ++j) bv[j] = bf2f(bi[n0 + 64 * wc + 16 * j + lrow]);
#pragma unroll
  for (int i = 0; i < 4; ++i) {
    int row = m0 + 64 * wr + 16 * i + 4 * quad;
#pragma unroll
    for (int j = 0; j < 4; ++j) {
      int col = n0 + 64 * wc + 16 * j + lrow;
#pragma unroll
      for (int r = 0; r < 4; ++r)
        C[(size_t)(row + r) * 1024 + col] = acc[i][j][r] + bv[j];
    }
  }
}

extern "C" void kernel_launch(void* const* d_in, const int* in_sizes, int n_in,
                              void* d_out, int out_size, void* d_ws, size_t ws_size,
                              hipStream_t stream) {
  (void)in_sizes; (void)n_in; (void)out_size; (void)ws_size;
  const size_t M1 = 1048576u;
  u16* ws = (u16*)d_ws;
  u16* wt    = ws;             // [6][1024,1024]: Wa_qk*s, Wa_v, Wb_qk, Wb_v, Wa_o, Wb_o (T)
  u16* wtA   = wt;
  u16* wtB   = wt + 2 * M1;
  u16* wtO   = wt + 4 * M1;
  u16* biasQ = ws + 6 * M1;    // [2][2048]
  u16* biasO = ws + 6 * M1 + 4096;  // [2][1024]
  u16* ab    = ws + 7 * M1;    // [2][4096,1024] bf16 inputs (dead after QKV)
  u16* vt    = ab;             // alias: [2][bh][64][2048]
  u16* qkbuf = ws + 15 * M1;   // [2][bh][2048][64]
  u16* vbuf  = ws + 23 * M1;   // [2][bh][2048][64] (dead after transpose_v)
  u16* ctx   = vbuf;           // alias: [2][4096,1024]

  dim3 blk(256);
  k_prep<<<dim3(5656), blk, 0, stream>>>(
      (const float*)d_in[0], (const float*)d_in[1], ab,
      (const float*)d_in[2], (const float*)d_in[4], (const float*)d_in[6],
      (const float*)d_in[8], (const float*)d_in[10], (const float*)d_in[12], wt,
      (const float*)d_in[3], (const float*)d_in[5], (const float*)d_in[7],
      (const float*)d_in[9], (const float*)d_in[11], (const float*)d_in[13], biasQ);
  k_gemm_qkv<<<dim3(16, 32, 2), blk, 0, stream>>>(ab, wtA, wtB, biasQ, qkbuf, vbuf);
  k_transpose_v<<<dim3(32, 64), blk, 0, stream>>>(vbuf, vt);
  k_attn<<<dim3(32, 16, 2), blk, 0, stream>>>(qkbuf, vt, ctx);
  k_gemm_o<<<dim3(8, 32, 2), blk, 0, stream>>>(ctx, wtO, biasO, (float*)d_out);
}